// Round 3
// baseline (179.404 us; speedup 1.0000x reference)
//
#include <hip/hip_runtime.h>

typedef int   i32x4 __attribute__((ext_vector_type(4)));
typedef int   i32x8 __attribute__((ext_vector_type(8)));
typedef float f32x16 __attribute__((ext_vector_type(16)));

#define D_DIM 256
#define LOG2E 1.4426950408889634f
#define LN2   0.6931471805599453f
// Transposed workspace layout: [strip of 128 rows][kc16 0..15][row 0..127][16B]
#define STRIP_BYTES 32768
#define GRID2 4096          // siglip grid: 64x64 tiles of 256x256

#if __has_builtin(__builtin_amdgcn_exp2f)
static __device__ __forceinline__ float exp2_fast(float x) { return __builtin_amdgcn_exp2f(x); }
#else
static __device__ __forceinline__ float exp2_fast(float x) { return __expf(x * LN2); }
#endif
#if __has_builtin(__builtin_amdgcn_logf)
static __device__ __forceinline__ float log2_fast(float x) { return __builtin_amdgcn_logf(x); }
#else
static __device__ __forceinline__ float log2_fast(float x) { return __logf(x) * LOG2E; }
#endif

#if __has_builtin(__builtin_amdgcn_cvt_pk_fp8_f32)
static __device__ __forceinline__ unsigned int pack4_fp8(float a, float b, float c, float d) {
    int v = 0;
    v = __builtin_amdgcn_cvt_pk_fp8_f32(a, b, v, false);
    v = __builtin_amdgcn_cvt_pk_fp8_f32(c, d, v, true);
    return (unsigned int)v;
}
#else
#include <hip/hip_fp8.h>
static __device__ __forceinline__ unsigned char cv1(float x) {
    __hip_fp8_e4m3 f(x);
    union { __hip_fp8_e4m3 f; unsigned char b; } u; u.f = f; return u.b;
}
static __device__ __forceinline__ unsigned int pack4_fp8(float a, float b, float c, float d) {
    return (unsigned int)cv1(a) | ((unsigned int)cv1(b) << 8) |
           ((unsigned int)cv1(c) << 16) | ((unsigned int)cv1(d) << 24);
}
#endif

// K=64 fp8 MFMA (32x32): MX-scaled if available, else 4x K=16 non-scaled.
static __device__ __forceinline__ f32x16 mfma_fp8_32x32_k64(i32x8 a, i32x8 b, f32x16 c) {
#if __has_builtin(__builtin_amdgcn_mfma_scale_f32_32x32x64_f8f6f4)
    return __builtin_amdgcn_mfma_scale_f32_32x32x64_f8f6f4(a, b, c, 0, 0, 0, 127, 0, 127);
#else
    union { i32x8 v; long l[4]; } ua, ub;
    ua.v = a; ub.v = b;
#pragma unroll
    for (int s = 0; s < 4; ++s)
        c = __builtin_amdgcn_mfma_f32_32x32x16_fp8_fp8(ua.l[s], ub.l[s], c, 0, 0, 0);
    return c;
#endif
}

// Kernel 1: L2-normalize fp32 -> fp8 e4m3, k-major strip layout:
// byte(row, k) -> strip(row>>7)*32768 + (k>>4)*2048 + (row&127)*16 + (k&15).
// One ROW per WAVE: lane i loads float4 #i of the row (1 KB coalesced per
// wave load instruction). Full-wave shfl reduce for the norm; each lane
// packs its own 4 bytes -> one aligned u32 store.
__global__ __launch_bounds__(256) void norm_cast_kernel(
    const float* __restrict__ img, const float* __restrict__ txt,
    unsigned char* __restrict__ Ab, unsigned char* __restrict__ Bb, int N)
{
    const int wave = threadIdx.x >> 6;
    const int lane = threadIdx.x & 63;
    int gRow = blockIdx.x * 4 + wave;   // 0..2N-1, wave-uniform

    const float* src;
    unsigned char* dstB;
    int row;
    if (gRow < N) { row = gRow;     src = img + (size_t)row * D_DIM; dstB = Ab; }
    else          { row = gRow - N; src = txt + (size_t)row * D_DIM; dstB = Bb; }

    float4 v = ((const float4*)src)[lane];
    float ss = v.x*v.x + v.y*v.y + v.z*v.z + v.w*v.w;
#pragma unroll
    for (int off = 1; off < 64; off <<= 1)
        ss += __shfl_xor(ss, off, 64);
    float inv = 1.0f / fmaxf(sqrtf(ss), 1e-12f);   // F.normalize eps

    // lane i holds k = 4i..4i+3: chunk = i>>2, byte-in-chunk = (i&3)*4.
    unsigned int w = pack4_fp8(v.x*inv, v.y*inv, v.z*inv, v.w*inv);
    unsigned char* dst = dstB + (size_t)(row >> 7) * STRIP_BYTES
                       + (lane >> 2) * 2048 + (row & 127) * 16 + (lane & 3) * 4;
    *(unsigned int*)dst = w;
}

// Kernel 2 (R3): 256x256 tile fp8-MX Gram + softplus-sum + inline diag.
// vs the 128x128 version (101 us): L2->LDS staging traffic halves
// (16384 x 64 KB = 1 GB  ->  4096 x 128 KB = 512 MB ~= the 29-us MFMA floor)
// and each barrier pair covers 8 MFMAs/wave instead of 4 (better latency
// overlap). 8 waves (2 row-halves x 4 col-quarters), each owns 128x64 of C:
// acc[4][2] f32x16 = 128 VGPRs; __launch_bounds__(512,2) -> 256-VGPR cap,
// 1 block/CU (LDS 64 KB double-buffered).
// Per-block partial is STORED (plain, contention-free) — NOT any same-address
// atomic: 16384 same-address RMWs serialize at ~13 ns each (R1's
// atomicAdd(counter)-based last-block-done regressed to 390 us).
__global__ __launch_bounds__(512, 2) void siglip_loss_kernel(
    const unsigned char* __restrict__ A, const unsigned char* __restrict__ B,
    const float* __restrict__ t_prime, const float* __restrict__ bias,
    float* __restrict__ partials, int N)
{
    // Chunk layout (per 64-B K-chunk): [kcl 0..3][half 0..1][row 0..127][16B]
    // = 16 KB per operand; kc16-plane stride 4096, half stride 2048.
    __shared__ unsigned char As[2][16384];
    __shared__ unsigned char Bs[2][16384];
    __shared__ float red[8];

    const int tid  = threadIdx.x;
    const int wave = tid >> 6;        // 0..7
    const int lane = tid & 63;
    const int r31  = lane & 31;
    const int g    = lane >> 5;       // selects kc16 pair {2g, 2g+1}
    const int wm   = wave >> 2;       // 0..1 row half (128 rows)
    const int wn   = wave & 3;        // 0..3 col quarter (64 cols)

    // 8x8 supertile swizzle for L2 locality (grid 4096 = 64x64 tiles).
    const int bid = blockIdx.x;
    const int st  = bid >> 6;
    const int l2  = bid & 63;
    const int bx  = (st & 7) * 8 + (l2 & 7);
    const int by  = (st >> 3) * 8 + (l2 >> 3);

    // Stage K-chunk c: 32 KB = 32 x 1KB wave-loads, 4 per wave.
    // A planes l=0..15, B planes l=16..31. Plane l covers LDS bytes
    // [l*1024, +1024) = (kcl = l>>2, half = (l>>1)&1, inner = (l&1)*1024);
    // global source = strip(2*b + half) + (4c + kcl)*2048 + inner.
    auto stage = [&](int buf, int c) {
#pragma unroll
        for (int li = 0; li < 4; ++li) {
            int l = wave * 4 + li;            // 0..31
            int lb = l & 15;
            int kcl   = lb >> 2;
            int half  = (lb >> 1) & 1;
            int inner = (lb & 1) * 1024;
            if (l < 16) {
                const unsigned char* src = A + (size_t)(2 * by + half) * STRIP_BYTES
                                         + (4 * c + kcl) * 2048 + inner + lane * 16;
                __builtin_amdgcn_global_load_lds(
                    (const __attribute__((address_space(1))) unsigned int*)src,
                    (__attribute__((address_space(3))) unsigned int*)&As[buf][l * 1024],
                    16, 0, 0);
            } else {
                const unsigned char* src = B + (size_t)(2 * bx + half) * STRIP_BYTES
                                         + (4 * c + kcl) * 2048 + inner + lane * 16;
                __builtin_amdgcn_global_load_lds(
                    (const __attribute__((address_space(1))) unsigned int*)src,
                    (__attribute__((address_space(3))) unsigned int*)&Bs[buf][lb * 1024],
                    16, 0, 0);
            }
        }
    };

    stage(0, 0);

    // Fragment LDS offsets. Tile row for sub-tile i: wm*128 + i*32 + r31
    // -> half = wm, row-in-half = i*32 + r31. Tile col for j:
    // wn*64 + j*32 + r31 -> half = wn>>1, row-in-half = (wn&1)*64 + j*32 + r31.
    // kc16 pair {2g, 2g+1} -> base plane offset g*8192, second at +4096.
    int a_off[4], b_off[2];
#pragma unroll
    for (int i = 0; i < 4; ++i)
        a_off[i] = g * 8192 + wm * 2048 + (i * 32 + r31) * 16;
#pragma unroll
    for (int j = 0; j < 2; ++j)
        b_off[j] = g * 8192 + (wn >> 1) * 2048 + ((wn & 1) * 64 + j * 32 + r31) * 16;

    f32x16 acc[4][2] = {};
    union F { i32x8 v8; i32x4 v4[2]; };

#pragma unroll 1
    for (int c = 0; c < 4; ++c) {
        __syncthreads();                    // publishes buffer c&1
        if (c < 3) stage((c + 1) & 1, c + 1);

        const unsigned char* as = As[c & 1];
        const unsigned char* bs = Bs[c & 1];
        F a[4], b[2];
#pragma unroll
        for (int j = 0; j < 2; ++j) {
            b[j].v4[0] = *(const i32x4*)&bs[b_off[j]];
            b[j].v4[1] = *(const i32x4*)&bs[b_off[j] + 4096];
        }
#pragma unroll
        for (int i = 0; i < 4; ++i) {
            a[i].v4[0] = *(const i32x4*)&as[a_off[i]];
            a[i].v4[1] = *(const i32x4*)&as[a_off[i] + 4096];
        }
        __builtin_amdgcn_s_setprio(1);
#pragma unroll
        for (int i = 0; i < 4; ++i)
#pragma unroll
            for (int j = 0; j < 2; ++j)
                acc[i][j] = mfma_fp8_32x32_k64(a[i].v8, b[j].v8, acc[i][j]);
        __builtin_amdgcn_s_setprio(0);
    }

    // Epilogue: z2 = s2*acc + b2 (log2 domain); log2 of products of 8.
    const float s2 = __expf(t_prime[0]) * LOG2E;
    const float b2 = bias[0] * LOG2E;
    float local = 0.0f;
#pragma unroll
    for (int i = 0; i < 4; ++i)
#pragma unroll
        for (int j = 0; j < 2; ++j)
#pragma unroll
            for (int g2 = 0; g2 < 2; ++g2) {
                float x[8];
#pragma unroll
                for (int e = 0; e < 8; ++e)
                    x[e] = exp2_fast(fmaf(s2, acc[i][j][g2 * 8 + e], b2));
                float p = 1.0f + x[0];
#pragma unroll
                for (int e = 1; e < 8; ++e)
                    p = fmaf(p, x[e], p);      // p *= (1 + x[e])
                local += log2_fast(p);
            }

    // Diagonal tiles: softplus(-z) = softplus(z) - z -> subtract z2.
    if (by == bx) {
#pragma unroll
        for (int i = 0; i < 4; ++i)
#pragma unroll
            for (int j = 0; j < 2; ++j)
#pragma unroll
                for (int r = 0; r < 16; ++r) {
                    // 32x32 C/D layout (m74/m101): col = lane&31,
                    // row = (r&3) + 8*(r>>2) + 4*(lane>>5)
                    int rowf = (r & 3) + 8 * (r >> 2) + 4 * g;
                    int grow = wm * 128 + i * 32 + rowf;
                    int gcol = wn * 64 + j * 32 + r31;
                    if (grow == gcol) local -= fmaf(s2, acc[i][j][r], b2);
                }
    }

#pragma unroll
    for (int off = 32; off > 0; off >>= 1)
        local += __shfl_xor(local, off, 64);
    if (lane == 0) red[wave] = local;
    __syncthreads();
    if (tid == 0) {
        float t = 0.0f;
#pragma unroll
        for (int w = 0; w < 8; ++w) t += red[w];
        partials[bid] = t;                 // plain store, no atomics
    }
}

// Kernel 3: reduce 4096 per-block partials -> out[0]. One block, ~2 us.
__global__ __launch_bounds__(1024) void reduce_kernel(
    const float* __restrict__ partials, float* __restrict__ out, int N)
{
    __shared__ float red[16];
    const int tid  = threadIdx.x;
    const int wave = tid >> 6;
    const int lane = tid & 63;
    float s = 0.0f;
#pragma unroll 4
    for (int i = tid; i < GRID2; i += 1024)
        s += partials[i];
#pragma unroll
    for (int off = 32; off > 0; off >>= 1)
        s += __shfl_xor(s, off, 64);
    if (lane == 0) red[wave] = s;
    __syncthreads();
    if (tid == 0) {
        float t = 0.0f;
#pragma unroll
        for (int w = 0; w < 16; ++w) t += red[w];
        out[0] = t * (LN2 / (float)N);
    }
}

extern "C" void kernel_launch(void* const* d_in, const int* in_sizes, int n_in,
                              void* d_out, int out_size, void* d_ws, size_t ws_size,
                              hipStream_t stream) {
    const float* img = (const float*)d_in[0];
    const float* txt = (const float*)d_in[1];
    const float* tp  = (const float*)d_in[2];
    const float* bs  = (const float*)d_in[3];
    float* out = (float*)d_out;
    int N = in_sizes[0] / D_DIM;    // 16384

    unsigned char* Ab = (unsigned char*)d_ws;       // 4 MB (k-major strips)
    unsigned char* Bb = Ab + (size_t)N * D_DIM;     // +4 MB
    float* partials   = (float*)(Bb + (size_t)N * D_DIM);   // 16 KB

    norm_cast_kernel<<<(2 * N) / 4, 256, 0, stream>>>(img, txt, Ab, Bb, N);
    siglip_loss_kernel<<<GRID2, 512, 0, stream>>>(Ab, Bb, tp, bs, partials, N);
    reduce_kernel<<<1, 1024, 0, stream>>>(partials, out, N);
}

// Round 5
// 169.895 us; speedup vs baseline: 1.0560x; 1.0560x over previous
//
#include <hip/hip_runtime.h>

typedef int   i32x4 __attribute__((ext_vector_type(4)));
typedef int   i32x8 __attribute__((ext_vector_type(8)));
typedef float f32x16 __attribute__((ext_vector_type(16)));

#define D_DIM 256
#define LOG2E 1.4426950408889634f
#define LN2   0.6931471805599453f
// Transposed workspace layout: [strip of 128 rows][kc16 0..15][row 0..127][16B]
#define STRIP_BYTES 32768
#define NBLK 16384

#if __has_builtin(__builtin_amdgcn_exp2f)
static __device__ __forceinline__ float exp2_fast(float x) { return __builtin_amdgcn_exp2f(x); }
#else
static __device__ __forceinline__ float exp2_fast(float x) { return __expf(x * LN2); }
#endif
#if __has_builtin(__builtin_amdgcn_logf)
static __device__ __forceinline__ float log2_fast(float x) { return __builtin_amdgcn_logf(x); }
#else
static __device__ __forceinline__ float log2_fast(float x) { return __logf(x) * LOG2E; }
#endif

#if __has_builtin(__builtin_amdgcn_cvt_pk_fp8_f32)
static __device__ __forceinline__ unsigned int pack4_fp8(float a, float b, float c, float d) {
    int v = 0;
    v = __builtin_amdgcn_cvt_pk_fp8_f32(a, b, v, false);
    v = __builtin_amdgcn_cvt_pk_fp8_f32(c, d, v, true);
    return (unsigned int)v;
}
#else
#include <hip/hip_fp8.h>
static __device__ __forceinline__ unsigned char cv1(float x) {
    __hip_fp8_e4m3 f(x);
    union { __hip_fp8_e4m3 f; unsigned char b; } u; u.f = f; return u.b;
}
static __device__ __forceinline__ unsigned int pack4_fp8(float a, float b, float c, float d) {
    return (unsigned int)cv1(a) | ((unsigned int)cv1(b) << 8) |
           ((unsigned int)cv1(c) << 16) | ((unsigned int)cv1(d) << 24);
}
#endif

// K=64 fp8 MFMA (32x32): MX-scaled if available, else 4x K=16 non-scaled.
static __device__ __forceinline__ f32x16 mfma_fp8_32x32_k64(i32x8 a, i32x8 b, f32x16 c) {
#if __has_builtin(__builtin_amdgcn_mfma_scale_f32_32x32x64_f8f6f4)
    return __builtin_amdgcn_mfma_scale_f32_32x32x64_f8f6f4(a, b, c, 0, 0, 0, 127, 0, 127);
#else
    union { i32x8 v; long l[4]; } ua, ub;
    ua.v = a; ub.v = b;
#pragma unroll
    for (int s = 0; s < 4; ++s)
        c = __builtin_amdgcn_mfma_f32_32x32x16_fp8_fp8(ua.l[s], ub.l[s], c, 0, 0, 0);
    return c;
#endif
}

// Kernel 1 (R5: ILP-4): L2-normalize fp32 -> fp8 e4m3, k-major strip layout:
// byte(row, k) -> strip(row>>7)*32768 + (k>>4)*2048 + (row&127)*16 + (k&15).
// FOUR rows per wave: the single-row version's critical path was one float4
// load (~900 cy HBM) + a 6-deep dependent shfl_xor chain (~30 cy each) for
// only ~40 issued instructions — pure latency. Here the 4 loads issue
// back-to-back and the 4 independent reduction chains pipeline, so the
// chain latency is paid ~once, not 4x. Per-row math/layout is byte-identical
// to the verified kernel. NOTE (R4 lesson): no cooperative launch — it
// silently no-ops in this harness (out stayed memset-0).
__global__ __launch_bounds__(256) void norm_cast_kernel(
    const float* __restrict__ img, const float* __restrict__ txt,
    unsigned char* __restrict__ Ab, unsigned char* __restrict__ Bb, int N)
{
    const int wave = threadIdx.x >> 6;
    const int lane = threadIdx.x & 63;
    const int base = blockIdx.x * 16 + wave * 4;   // 4 rows per wave

    // Issue all 4 loads first (independent -> overlapped HBM latency).
    float4 v[4];
#pragma unroll
    for (int i = 0; i < 4; ++i) {
        int gRow = base + i;
        int row  = (gRow < N) ? gRow : gRow - N;
        const float* src = ((gRow < N) ? img : txt) + (size_t)row * D_DIM;
        v[i] = ((const float4*)src)[lane];
    }

    float ss[4];
#pragma unroll
    for (int i = 0; i < 4; ++i)
        ss[i] = v[i].x*v[i].x + v[i].y*v[i].y + v[i].z*v[i].z + v[i].w*v[i].w;

    // 4 independent butterfly chains, interleaved (pipelined DS latency).
#pragma unroll
    for (int off = 1; off < 64; off <<= 1) {
#pragma unroll
        for (int i = 0; i < 4; ++i)
            ss[i] += __shfl_xor(ss[i], off, 64);
    }

#pragma unroll
    for (int i = 0; i < 4; ++i) {
        int gRow = base + i;
        int row  = (gRow < N) ? gRow : gRow - N;
        unsigned char* dstB = (gRow < N) ? Ab : Bb;
        float inv = 1.0f / fmaxf(sqrtf(ss[i]), 1e-12f);   // F.normalize eps
        // lane holds k = 4*lane..4*lane+3: chunk = lane>>2, byte = (lane&3)*4.
        unsigned int w = pack4_fp8(v[i].x*inv, v[i].y*inv, v[i].z*inv, v[i].w*inv);
        unsigned char* dst = dstB + (size_t)(row >> 7) * STRIP_BYTES
                           + (lane >> 2) * 2048 + (row & 127) * 16 + (lane & 3) * 4;
        *(unsigned int*)dst = w;
    }
}

// Kernel 2: fp8-MX Gram + softplus-sum + inline diag (verified, 101 us).
// Per-block partial is STORED (coalesced, contention-free), NOT accumulated
// or counted via a same-address atomic: 16384 same-address device RMWs
// serialize at ~13 ns each (~218 us floor; R1's last-block-done
// atomicAdd(counter) regressed to 390 us the same way).
__global__ __launch_bounds__(256, 4) void siglip_loss_kernel(
    const unsigned char* __restrict__ A, const unsigned char* __restrict__ B,
    const float* __restrict__ t_prime, const float* __restrict__ bias,
    float* __restrict__ partials, int N)
{
    __shared__ unsigned char As[2][8192];   // [kc16 0..3][row 0..127][16B]
    __shared__ unsigned char Bs[2][8192];
    __shared__ float red[4];

    const int tid  = threadIdx.x;
    const int wave = tid >> 6;
    const int lane = tid & 63;
    const int r31  = lane & 31;
    const int g    = lane >> 5;       // k-group (2 kc16 chunks of the 4)
    const int wv   = wave >> 1;       // 0..1 row half
    const int wu   = wave & 1;        // 0..1 col half

    // 16x16 supertile swizzle for L2 locality (grid 16384 flat).
    const int bid = blockIdx.x;
    const int st  = bid >> 8;
    const int l2  = bid & 255;
    const int bx  = (st & 7) * 16 + (l2 & 15);
    const int by  = (st >> 3) * 16 + (l2 >> 4);
    const int rowBase = by * 128;
    const int colBase = bx * 128;

    const unsigned char* Astrip = A + (size_t)by * STRIP_BYTES;
    const unsigned char* Bstrip = B + (size_t)bx * STRIP_BYTES;

    // Stage K-chunk c (8 KB per operand = 8 x 1KB loads, 2 per wave each).
    auto stage = [&](int buf, int c) {
        const unsigned char* ga = Astrip + c * 8192;
        const unsigned char* gb = Bstrip + c * 8192;
#pragma unroll
        for (int l = 0; l < 2; ++l) {
            int idx = wave * 2 + l;   // 0..7
            __builtin_amdgcn_global_load_lds(
                (const __attribute__((address_space(1))) unsigned int*)(ga + idx * 1024 + lane * 16),
                (__attribute__((address_space(3))) unsigned int*)&As[buf][idx * 1024],
                16, 0, 0);
            __builtin_amdgcn_global_load_lds(
                (const __attribute__((address_space(1))) unsigned int*)(gb + idx * 1024 + lane * 16),
                (__attribute__((address_space(3))) unsigned int*)&Bs[buf][idx * 1024],
                16, 0, 0);
        }
    };

    stage(0, 0);

    // Fragment LDS offsets: kc_local = 2g (+1 for the second 16B half).
    int a_off[2], b_off[2];
#pragma unroll
    for (int i = 0; i < 2; ++i) a_off[i] = g * 4096 + (wv * 64 + i * 32 + r31) * 16;
#pragma unroll
    for (int j = 0; j < 2; ++j) b_off[j] = g * 4096 + (wu * 64 + j * 32 + r31) * 16;

    f32x16 acc[2][2] = {};
    union F { i32x8 v8; i32x4 v4[2]; };

#pragma unroll 1
    for (int c = 0; c < 4; ++c) {
        __syncthreads();                    // publishes buffer c&1
        if (c < 3) stage((c + 1) & 1, c + 1);

        const unsigned char* as = As[c & 1];
        const unsigned char* bs = Bs[c & 1];
        F a[2], b[2];
#pragma unroll
        for (int i = 0; i < 2; ++i) {
            a[i].v4[0] = *(const i32x4*)&as[a_off[i]];
            a[i].v4[1] = *(const i32x4*)&as[a_off[i] + 2048];
            b[i].v4[0] = *(const i32x4*)&bs[b_off[i]];
            b[i].v4[1] = *(const i32x4*)&bs[b_off[i] + 2048];
        }
#pragma unroll
        for (int i = 0; i < 2; ++i)
#pragma unroll
            for (int j = 0; j < 2; ++j)
                acc[i][j] = mfma_fp8_32x32_k64(a[i].v8, b[j].v8, acc[i][j]);
    }

    // Epilogue: z2 = s2*acc + b2 (log2 domain); log2 of products of 8.
    const float s2 = __expf(t_prime[0]) * LOG2E;
    const float b2 = bias[0] * LOG2E;
    float local = 0.0f;
#pragma unroll
    for (int i = 0; i < 2; ++i)
#pragma unroll
        for (int j = 0; j < 2; ++j)
#pragma unroll
            for (int g2 = 0; g2 < 2; ++g2) {
                float x[8];
#pragma unroll
                for (int e = 0; e < 8; ++e)
                    x[e] = exp2_fast(fmaf(s2, acc[i][j][g2 * 8 + e], b2));
                float p = 1.0f + x[0];
#pragma unroll
                for (int e = 1; e < 8; ++e)
                    p = fmaf(p, x[e], p);      // p *= (1 + x[e])
                local += log2_fast(p);
            }

    // Diagonal blocks: softplus(-z) = softplus(z) - z -> subtract z2.
    if (rowBase == colBase) {
#pragma unroll
        for (int i = 0; i < 2; ++i)
#pragma unroll
            for (int j = 0; j < 2; ++j)
#pragma unroll
                for (int r = 0; r < 16; ++r) {
                    // 32x32 C/D layout (m74/m101): col = lane&31,
                    // row = (r&3) + 8*(r>>2) + 4*(lane>>5)
                    int rowf = (r & 3) + 8 * (r >> 2) + 4 * g;
                    int grow = wv * 64 + i * 32 + rowf;
                    int gcol = wu * 64 + j * 32 + r31;
                    if (grow == gcol) local -= fmaf(s2, acc[i][j][r], b2);
                }
    }

#pragma unroll
    for (int off = 32; off > 0; off >>= 1)
        local += __shfl_xor(local, off, 64);
    if (lane == 0) red[wave] = local;
    __syncthreads();
    if (tid == 0)
        partials[bid] = (red[0] + red[1]) + (red[2] + red[3]);   // plain store
}

// Kernel 3: reduce 16384 per-block partials -> out[0]. One block, ~3 us.
__global__ __launch_bounds__(1024) void reduce_kernel(
    const float* __restrict__ partials, float* __restrict__ out, int N)
{
    __shared__ float red[16];
    const int tid  = threadIdx.x;
    const int wave = tid >> 6;
    const int lane = tid & 63;
    float s = 0.0f;
#pragma unroll 4
    for (int i = tid; i < NBLK; i += 1024)
        s += partials[i];
#pragma unroll
    for (int off = 32; off > 0; off >>= 1)
        s += __shfl_xor(s, off, 64);
    if (lane == 0) red[wave] = s;
    __syncthreads();
    if (tid == 0) {
        float t = 0.0f;
#pragma unroll
        for (int w = 0; w < 16; ++w) t += red[w];
        out[0] = t * (LN2 / (float)N);
    }
}

extern "C" void kernel_launch(void* const* d_in, const int* in_sizes, int n_in,
                              void* d_out, int out_size, void* d_ws, size_t ws_size,
                              hipStream_t stream) {
    const float* img = (const float*)d_in[0];
    const float* txt = (const float*)d_in[1];
    const float* tp  = (const float*)d_in[2];
    const float* bs  = (const float*)d_in[3];
    float* out = (float*)d_out;
    int N = in_sizes[0] / D_DIM;    // 16384

    unsigned char* Ab = (unsigned char*)d_ws;       // 4 MB (k-major strips)
    unsigned char* Bb = Ab + (size_t)N * D_DIM;     // +4 MB
    float* partials   = (float*)(Bb + (size_t)N * D_DIM);   // 64 KB

    norm_cast_kernel<<<(2 * N) / 16, 256, 0, stream>>>(img, txt, Ab, Bb, N);
    siglip_loss_kernel<<<NBLK, 256, 0, stream>>>(Ab, Bb, tp, bs, partials, N);
    reduce_kernel<<<1, 1024, 0, stream>>>(partials, out, N);
}

// Round 6
// 165.487 us; speedup vs baseline: 1.0841x; 1.0266x over previous
//
#include <hip/hip_runtime.h>

typedef int   i32x4 __attribute__((ext_vector_type(4)));
typedef int   i32x8 __attribute__((ext_vector_type(8)));
typedef float f32x16 __attribute__((ext_vector_type(16)));

#define D_DIM 256
#define LOG2E 1.4426950408889634f
#define LN2   0.6931471805599453f
// Transposed workspace layout: [strip of 128 rows][kc16 0..15][row 0..127][16B]
#define STRIP_BYTES 32768
#define NBLK 16384

#if __has_builtin(__builtin_amdgcn_exp2f)
static __device__ __forceinline__ float exp2_fast(float x) { return __builtin_amdgcn_exp2f(x); }
#else
static __device__ __forceinline__ float exp2_fast(float x) { return __expf(x * LN2); }
#endif
#if __has_builtin(__builtin_amdgcn_logf)
static __device__ __forceinline__ float log2_fast(float x) { return __builtin_amdgcn_logf(x); }
#else
static __device__ __forceinline__ float log2_fast(float x) { return __logf(x) * LOG2E; }
#endif

#if __has_builtin(__builtin_amdgcn_cvt_pk_fp8_f32)
static __device__ __forceinline__ unsigned int pack4_fp8(float a, float b, float c, float d) {
    int v = 0;
    v = __builtin_amdgcn_cvt_pk_fp8_f32(a, b, v, false);
    v = __builtin_amdgcn_cvt_pk_fp8_f32(c, d, v, true);
    return (unsigned int)v;
}
#else
#include <hip/hip_fp8.h>
static __device__ __forceinline__ unsigned char cv1(float x) {
    __hip_fp8_e4m3 f(x);
    union { __hip_fp8_e4m3 f; unsigned char b; } u; u.f = f; return u.b;
}
static __device__ __forceinline__ unsigned int pack4_fp8(float a, float b, float c, float d) {
    return (unsigned int)cv1(a) | ((unsigned int)cv1(b) << 8) |
           ((unsigned int)cv1(c) << 16) | ((unsigned int)cv1(d) << 24);
}
#endif

// K=64 fp8 MFMA (32x32): MX-scaled if available, else 4x K=16 non-scaled.
static __device__ __forceinline__ f32x16 mfma_fp8_32x32_k64(i32x8 a, i32x8 b, f32x16 c) {
#if __has_builtin(__builtin_amdgcn_mfma_scale_f32_32x32x64_f8f6f4)
    return __builtin_amdgcn_mfma_scale_f32_32x32x64_f8f6f4(a, b, c, 0, 0, 0, 127, 0, 127);
#else
    union { i32x8 v; long l[4]; } ua, ub;
    ua.v = a; ub.v = b;
#pragma unroll
    for (int s = 0; s < 4; ++s)
        c = __builtin_amdgcn_mfma_f32_32x32x16_fp8_fp8(ua.l[s], ub.l[s], c, 0, 0, 0);
    return c;
#endif
}

// Counted waitcnt: loads complete oldest-first for vmcnt purposes (m135),
// so vmcnt(N) guarantees exactly the (outstanding-N) oldest are done.
#define VMWAIT(n) asm volatile("s_waitcnt vmcnt(" #n ")" ::: "memory")

// Kernel 1 (ILP-4): L2-normalize fp32 -> fp8 e4m3, k-major strip layout:
// byte(row, k) -> strip(row>>7)*32768 + (k>>4)*2048 + (row&127)*16 + (k&15).
// Four rows per wave; 4 independent loads / reductions pipelined.
// NOTE (R4 lesson): no cooperative launch — silently no-ops in this harness.
__global__ __launch_bounds__(256) void norm_cast_kernel(
    const float* __restrict__ img, const float* __restrict__ txt,
    unsigned char* __restrict__ Ab, unsigned char* __restrict__ Bb, int N)
{
    const int wave = threadIdx.x >> 6;
    const int lane = threadIdx.x & 63;
    const int base = blockIdx.x * 16 + wave * 4;   // 4 rows per wave

    float4 v[4];
#pragma unroll
    for (int i = 0; i < 4; ++i) {
        int gRow = base + i;
        int row  = (gRow < N) ? gRow : gRow - N;
        const float* src = ((gRow < N) ? img : txt) + (size_t)row * D_DIM;
        v[i] = ((const float4*)src)[lane];
    }

    float ss[4];
#pragma unroll
    for (int i = 0; i < 4; ++i)
        ss[i] = v[i].x*v[i].x + v[i].y*v[i].y + v[i].z*v[i].z + v[i].w*v[i].w;

#pragma unroll
    for (int off = 1; off < 64; off <<= 1) {
#pragma unroll
        for (int i = 0; i < 4; ++i)
            ss[i] += __shfl_xor(ss[i], off, 64);
    }

#pragma unroll
    for (int i = 0; i < 4; ++i) {
        int gRow = base + i;
        int row  = (gRow < N) ? gRow : gRow - N;
        unsigned char* dstB = (gRow < N) ? Ab : Bb;
        float inv = 1.0f / fmaxf(sqrtf(ss[i]), 1e-12f);   // F.normalize eps
        unsigned int w = pack4_fp8(v[i].x*inv, v[i].y*inv, v[i].z*inv, v[i].w*inv);
        unsigned char* dst = dstB + (size_t)(row >> 7) * STRIP_BYTES
                           + (lane >> 2) * 2048 + (row & 127) * 16 + (lane & 3) * 4;
        *(unsigned int*)dst = w;
    }
}

// Kernel 2 (R6): fp8-MX Gram + softplus-sum + inline diag.
// Pipeline rework: the 2-buffer __syncthreads loop drained vmcnt(0) at every
// barrier, so each 16-KB chunk paid fresh L2 latency (~3800 cy/tile measured
// vs ~1200 overlapped floor). Now a 3-buffer ring with COUNTED vmcnt + raw
// s_barrier keeps later chunks' loads in flight across barriers (T3/T4):
//   issue c0,c1,c2 (12 loads/wave) -> wait vmcnt(8): c0 ready -> bar -> MFMA
//   wait vmcnt(4): c1 ready -> bar -> stage c3 into buf0 -> MFMA
//   wait vmcnt(4): c2 ready -> bar -> MFMA;  wait vmcnt(0) -> bar -> MFMA.
// LDS 48 KB -> still 3 blocks/CU (same 12 waves/CU as measured; avoids the
// 64-KB/2-block occupancy cliff).
// Per-block partial is STORED (plain, contention-free) — NEVER a same-address
// RMW: 16384 same-address atomics serialize ~13 ns each (218/390-us traps).
__global__ __launch_bounds__(256, 3) void siglip_loss_kernel(
    const unsigned char* __restrict__ A, const unsigned char* __restrict__ B,
    const float* __restrict__ t_prime, const float* __restrict__ bias,
    float* __restrict__ partials, int N)
{
    __shared__ unsigned char As[3][8192];   // ring: chunk c -> buf c%3
    __shared__ unsigned char Bs[3][8192];   // [kc16 0..3][row 0..127][16B]
    __shared__ float red[4];

    const int tid  = threadIdx.x;
    const int wave = tid >> 6;
    const int lane = tid & 63;
    const int r31  = lane & 31;
    const int g    = lane >> 5;       // k-group (2 kc16 chunks of the 4)
    const int wv   = wave >> 1;       // 0..1 row half
    const int wu   = wave & 1;        // 0..1 col half

    // 16x16 supertile swizzle for L2 locality (grid 16384 flat).
    const int bid = blockIdx.x;
    const int st  = bid >> 8;
    const int l2  = bid & 255;
    const int bx  = (st & 7) * 16 + (l2 & 15);
    const int by  = (st >> 3) * 16 + (l2 >> 4);
    const int rowBase = by * 128;
    const int colBase = bx * 128;

    const unsigned char* Astrip = A + (size_t)by * STRIP_BYTES;
    const unsigned char* Bstrip = B + (size_t)bx * STRIP_BYTES;

    // Stage K-chunk c into ring buffer buf: 16 KB = 32 x 1KB wave-loads,
    // exactly 4 global_load_lds per wave (the vmcnt bookkeeping unit).
    auto stage = [&](int buf, int c) {
        const unsigned char* ga = Astrip + c * 8192;
        const unsigned char* gb = Bstrip + c * 8192;
#pragma unroll
        for (int l = 0; l < 2; ++l) {
            int idx = wave * 2 + l;   // 0..7
            __builtin_amdgcn_global_load_lds(
                (const __attribute__((address_space(1))) unsigned int*)(ga + idx * 1024 + lane * 16),
                (__attribute__((address_space(3))) unsigned int*)&As[buf][idx * 1024],
                16, 0, 0);
            __builtin_amdgcn_global_load_lds(
                (const __attribute__((address_space(1))) unsigned int*)(gb + idx * 1024 + lane * 16),
                (__attribute__((address_space(3))) unsigned int*)&Bs[buf][idx * 1024],
                16, 0, 0);
        }
    };

    // Fragment LDS offsets (buffer-relative): kc_local = 2g (+1 at +2048).
    int a_off[2], b_off[2];
#pragma unroll
    for (int i = 0; i < 2; ++i) a_off[i] = g * 4096 + (wv * 64 + i * 32 + r31) * 16;
#pragma unroll
    for (int j = 0; j < 2; ++j) b_off[j] = g * 4096 + (wu * 64 + j * 32 + r31) * 16;

    f32x16 acc[2][2] = {};
    union F { i32x8 v8; i32x4 v4[2]; };

    auto body = [&](const unsigned char* as, const unsigned char* bs) {
        F a[2], b[2];
#pragma unroll
        for (int i = 0; i < 2; ++i) {
            a[i].v4[0] = *(const i32x4*)&as[a_off[i]];
            a[i].v4[1] = *(const i32x4*)&as[a_off[i] + 2048];
            b[i].v4[0] = *(const i32x4*)&bs[b_off[i]];
            b[i].v4[1] = *(const i32x4*)&bs[b_off[i] + 2048];
        }
#pragma unroll
        for (int i = 0; i < 2; ++i)
#pragma unroll
            for (int j = 0; j < 2; ++j)
                acc[i][j] = mfma_fp8_32x32_k64(a[i].v8, b[j].v8, acc[i][j]);
    };

    // Prologue: 3 chunks in flight (12 loads/wave).
    stage(0, 0); stage(1, 1); stage(2, 2);

    // c=0: oldest 4 (c0) done when <=8 outstanding.
    VMWAIT(8);
    __builtin_amdgcn_s_barrier();
    body(As[0], Bs[0]);

    // c=1: c1 done when <=4 outstanding (c2 may remain).
    VMWAIT(4);
    __builtin_amdgcn_s_barrier();     // also: all waves done reading buf0
    stage(0, 3);                      // chunk 3 -> buf0 (now safe)
    body(As[1], Bs[1]);

    // c=2: outstanding <= {c2,c3}=8; <=4 left means c2 done.
    VMWAIT(4);
    __builtin_amdgcn_s_barrier();
    body(As[2], Bs[2]);

    // c=3: drain.
    VMWAIT(0);
    __builtin_amdgcn_s_barrier();
    body(As[0], Bs[0]);

    // Epilogue: z2 = s2*acc + b2 (log2 domain); log2 of products of 8.
    const float s2 = __expf(t_prime[0]) * LOG2E;
    const float b2 = bias[0] * LOG2E;
    float local = 0.0f;
#pragma unroll
    for (int i = 0; i < 2; ++i)
#pragma unroll
        for (int j = 0; j < 2; ++j)
#pragma unroll
            for (int g2 = 0; g2 < 2; ++g2) {
                float x[8];
#pragma unroll
                for (int e = 0; e < 8; ++e)
                    x[e] = exp2_fast(fmaf(s2, acc[i][j][g2 * 8 + e], b2));
                float p = 1.0f + x[0];
#pragma unroll
                for (int e = 1; e < 8; ++e)
                    p = fmaf(p, x[e], p);      // p *= (1 + x[e])
                local += log2_fast(p);
            }

    // Diagonal blocks: softplus(-z) = softplus(z) - z -> subtract z2.
    if (rowBase == colBase) {
#pragma unroll
        for (int i = 0; i < 2; ++i)
#pragma unroll
            for (int j = 0; j < 2; ++j)
#pragma unroll
                for (int r = 0; r < 16; ++r) {
                    // 32x32 C/D layout (m74/m101): col = lane&31,
                    // row = (r&3) + 8*(r>>2) + 4*(lane>>5)
                    int rowf = (r & 3) + 8 * (r >> 2) + 4 * g;
                    int grow = wv * 64 + i * 32 + rowf;
                    int gcol = wu * 64 + j * 32 + r31;
                    if (grow == gcol) local -= fmaf(s2, acc[i][j][r], b2);
                }
    }

#pragma unroll
    for (int off = 32; off > 0; off >>= 1)
        local += __shfl_xor(local, off, 64);
    if (lane == 0) red[wave] = local;
    __syncthreads();
    if (tid == 0)
        partials[bid] = (red[0] + red[1]) + (red[2] + red[3]);   // plain store
}

// Kernel 3: reduce 16384 per-block partials -> out[0]. One block, ~3 us.
__global__ __launch_bounds__(1024) void reduce_kernel(
    const float* __restrict__ partials, float* __restrict__ out, int N)
{
    __shared__ float red[16];
    const int tid  = threadIdx.x;
    const int wave = tid >> 6;
    const int lane = tid & 63;
    float s = 0.0f;
#pragma unroll 4
    for (int i = tid; i < NBLK; i += 1024)
        s += partials[i];
#pragma unroll
    for (int off = 32; off > 0; off >>= 1)
        s += __shfl_xor(s, off, 64);
    if (lane == 0) red[wave] = s;
    __syncthreads();
    if (tid == 0) {
        float t = 0.0f;
#pragma unroll
        for (int w = 0; w < 16; ++w) t += red[w];
        out[0] = t * (LN2 / (float)N);
    }
}

extern "C" void kernel_launch(void* const* d_in, const int* in_sizes, int n_in,
                              void* d_out, int out_size, void* d_ws, size_t ws_size,
                              hipStream_t stream) {
    const float* img = (const float*)d_in[0];
    const float* txt = (const float*)d_in[1];
    const float* tp  = (const float*)d_in[2];
    const float* bs  = (const float*)d_in[3];
    float* out = (float*)d_out;
    int N = in_sizes[0] / D_DIM;    // 16384

    unsigned char* Ab = (unsigned char*)d_ws;       // 4 MB (k-major strips)
    unsigned char* Bb = Ab + (size_t)N * D_DIM;     // +4 MB
    float* partials   = (float*)(Bb + (size_t)N * D_DIM);   // 64 KB

    norm_cast_kernel<<<(2 * N) / 16, 256, 0, stream>>>(img, txt, Ab, Bb, N);
    siglip_loss_kernel<<<NBLK, 256, 0, stream>>>(Ab, Bb, tp, bs, partials, N);
    reduce_kernel<<<1, 1024, 0, stream>>>(partials, out, N);
}

// Round 7
// 163.219 us; speedup vs baseline: 1.0992x; 1.0139x over previous
//
#include <hip/hip_runtime.h>

typedef int   i32x4 __attribute__((ext_vector_type(4)));
typedef int   i32x8 __attribute__((ext_vector_type(8)));
typedef float f32x16 __attribute__((ext_vector_type(16)));

#define D_DIM 256
#define LOG2E 1.4426950408889634f
#define LN2   0.6931471805599453f
// Transposed workspace layout: [strip of 128 rows][kc16 0..15][row 0..127][16B]
#define STRIP_BYTES 32768
#define NBLK 16384

#if __has_builtin(__builtin_amdgcn_exp2f)
static __device__ __forceinline__ float exp2_fast(float x) { return __builtin_amdgcn_exp2f(x); }
#else
static __device__ __forceinline__ float exp2_fast(float x) { return __expf(x * LN2); }
#endif
#if __has_builtin(__builtin_amdgcn_logf)
static __device__ __forceinline__ float log2_fast(float x) { return __builtin_amdgcn_logf(x); }
#else
static __device__ __forceinline__ float log2_fast(float x) { return __logf(x) * LOG2E; }
#endif

#if __has_builtin(__builtin_amdgcn_cvt_pk_fp8_f32)
static __device__ __forceinline__ unsigned int pack4_fp8(float a, float b, float c, float d) {
    int v = 0;
    v = __builtin_amdgcn_cvt_pk_fp8_f32(a, b, v, false);
    v = __builtin_amdgcn_cvt_pk_fp8_f32(c, d, v, true);
    return (unsigned int)v;
}
#else
#include <hip/hip_fp8.h>
static __device__ __forceinline__ unsigned char cv1(float x) {
    __hip_fp8_e4m3 f(x);
    union { __hip_fp8_e4m3 f; unsigned char b; } u; u.f = f; return u.b;
}
static __device__ __forceinline__ unsigned int pack4_fp8(float a, float b, float c, float d) {
    return (unsigned int)cv1(a) | ((unsigned int)cv1(b) << 8) |
           ((unsigned int)cv1(c) << 16) | ((unsigned int)cv1(d) << 24);
}
#endif

// K=64 fp8 MFMA (32x32): MX-scaled if available, else 4x K=16 non-scaled.
static __device__ __forceinline__ f32x16 mfma_fp8_32x32_k64(i32x8 a, i32x8 b, f32x16 c) {
#if __has_builtin(__builtin_amdgcn_mfma_scale_f32_32x32x64_f8f6f4)
    return __builtin_amdgcn_mfma_scale_f32_32x32x64_f8f6f4(a, b, c, 0, 0, 0, 127, 0, 127);
#else
    union { i32x8 v; long l[4]; } ua, ub;
    ua.v = a; ub.v = b;
#pragma unroll
    for (int s = 0; s < 4; ++s)
        c = __builtin_amdgcn_mfma_f32_32x32x16_fp8_fp8(ua.l[s], ub.l[s], c, 0, 0, 0);
    return c;
#endif
}

// Counted waitcnt: loads complete oldest-first for vmcnt purposes (m135),
// so vmcnt(N) guarantees the (outstanding-N) oldest are done. Per-wave wait
// + s_barrier => collective completion (pattern proven in R6).
#define VMWAIT(n) asm volatile("s_waitcnt vmcnt(" #n ")" ::: "memory")

// Kernel 1 (ILP-4): L2-normalize fp32 -> fp8 e4m3, k-major strip layout:
// byte(row, k) -> strip(row>>7)*32768 + (k>>4)*2048 + (row&127)*16 + (k&15).
// Four rows per wave; 4 independent loads / reductions pipelined.
// NOTE (R4 lesson): no cooperative launch — silently no-ops in this harness.
__global__ __launch_bounds__(256) void norm_cast_kernel(
    const float* __restrict__ img, const float* __restrict__ txt,
    unsigned char* __restrict__ Ab, unsigned char* __restrict__ Bb, int N)
{
    const int wave = threadIdx.x >> 6;
    const int lane = threadIdx.x & 63;
    const int base = blockIdx.x * 16 + wave * 4;   // 4 rows per wave

    float4 v[4];
#pragma unroll
    for (int i = 0; i < 4; ++i) {
        int gRow = base + i;
        int row  = (gRow < N) ? gRow : gRow - N;
        const float* src = ((gRow < N) ? img : txt) + (size_t)row * D_DIM;
        v[i] = ((const float4*)src)[lane];
    }

    float ss[4];
#pragma unroll
    for (int i = 0; i < 4; ++i)
        ss[i] = v[i].x*v[i].x + v[i].y*v[i].y + v[i].z*v[i].z + v[i].w*v[i].w;

#pragma unroll
    for (int off = 1; off < 64; off <<= 1) {
#pragma unroll
        for (int i = 0; i < 4; ++i)
            ss[i] += __shfl_xor(ss[i], off, 64);
    }

#pragma unroll
    for (int i = 0; i < 4; ++i) {
        int gRow = base + i;
        int row  = (gRow < N) ? gRow : gRow - N;
        unsigned char* dstB = (gRow < N) ? Ab : Bb;
        float inv = 1.0f / fmaxf(sqrtf(ss[i]), 1e-12f);   // F.normalize eps
        unsigned int w = pack4_fp8(v[i].x*inv, v[i].y*inv, v[i].z*inv, v[i].w*inv);
        unsigned char* dst = dstB + (size_t)(row >> 7) * STRIP_BYTES
                           + (lane >> 2) * 2048 + (row & 127) * 16 + (lane & 3) * 4;
        *(unsigned int*)dst = w;
    }
}

// Kernel 2 (R7): fp8-MX Gram + softplus-sum + inline diag.
// R6 proved counted-vmcnt prefetch helps (+MfmaUtil, +BW) but its 48-KB
// 3-buffer ring cut co-residency 4->3 blocks/CU and gave back most of the
// gain. R7 keeps BOTH: 2-buffer ring (32.8 KB -> 4 blocks/CU, 16 waves/CU)
// with depth-1 counted prefetch — one 16-KB chunk always in flight under
// each MFMA body, no vmcnt(0) drain until the final chunk:
//   stage c0,c1 | w(4) bar body(b0) | bar stage c2 w(4) bar body(b1)
//   | bar stage c3 w(4) bar body(b0) | w(0) bar body(b1)
// Per-block partial is STORED (plain, contention-free) — NEVER a same-address
// RMW: 16384 same-address atomics serialize ~13 ns each (218/390-us traps).
__global__ __launch_bounds__(256, 4) void siglip_loss_kernel(
    const unsigned char* __restrict__ A, const unsigned char* __restrict__ B,
    const float* __restrict__ t_prime, const float* __restrict__ bias,
    float* __restrict__ partials, int N)
{
    __shared__ unsigned char As[2][8192];   // [kc16 0..3][row 0..127][16B]
    __shared__ unsigned char Bs[2][8192];
    __shared__ float red[4];

    const int tid  = threadIdx.x;
    const int wave = tid >> 6;
    const int lane = tid & 63;
    const int r31  = lane & 31;
    const int g    = lane >> 5;       // k-group (2 kc16 chunks of the 4)
    const int wv   = wave >> 1;       // 0..1 row half
    const int wu   = wave & 1;        // 0..1 col half

    // 16x16 supertile swizzle for L2 locality (grid 16384 flat).
    const int bid = blockIdx.x;
    const int st  = bid >> 8;
    const int l2  = bid & 255;
    const int bx  = (st & 7) * 16 + (l2 & 15);
    const int by  = (st >> 3) * 16 + (l2 >> 4);
    const int rowBase = by * 128;
    const int colBase = bx * 128;

    const unsigned char* Astrip = A + (size_t)by * STRIP_BYTES;
    const unsigned char* Bstrip = B + (size_t)bx * STRIP_BYTES;

    // Stage K-chunk c into buffer buf: 16 KB = 32 x 1KB wave-loads,
    // exactly 4 global_load_lds per wave (the vmcnt bookkeeping unit).
    auto stage = [&](int buf, int c) {
        const unsigned char* ga = Astrip + c * 8192;
        const unsigned char* gb = Bstrip + c * 8192;
#pragma unroll
        for (int l = 0; l < 2; ++l) {
            int idx = wave * 2 + l;   // 0..7
            __builtin_amdgcn_global_load_lds(
                (const __attribute__((address_space(1))) unsigned int*)(ga + idx * 1024 + lane * 16),
                (__attribute__((address_space(3))) unsigned int*)&As[buf][idx * 1024],
                16, 0, 0);
            __builtin_amdgcn_global_load_lds(
                (const __attribute__((address_space(1))) unsigned int*)(gb + idx * 1024 + lane * 16),
                (__attribute__((address_space(3))) unsigned int*)&Bs[buf][idx * 1024],
                16, 0, 0);
        }
    };

    // Fragment LDS offsets (buffer-relative): kc_local = 2g (+1 at +2048).
    int a_off[2], b_off[2];
#pragma unroll
    for (int i = 0; i < 2; ++i) a_off[i] = g * 4096 + (wv * 64 + i * 32 + r31) * 16;
#pragma unroll
    for (int j = 0; j < 2; ++j) b_off[j] = g * 4096 + (wu * 64 + j * 32 + r31) * 16;

    f32x16 acc[2][2] = {};
    union F { i32x8 v8; i32x4 v4[2]; };

    auto body = [&](const unsigned char* as, const unsigned char* bs) {
        F a[2], b[2];
#pragma unroll
        for (int i = 0; i < 2; ++i) {
            a[i].v4[0] = *(const i32x4*)&as[a_off[i]];
            a[i].v4[1] = *(const i32x4*)&as[a_off[i] + 2048];
            b[i].v4[0] = *(const i32x4*)&bs[b_off[i]];
            b[i].v4[1] = *(const i32x4*)&bs[b_off[i] + 2048];
        }
#pragma unroll
        for (int i = 0; i < 2; ++i)
#pragma unroll
            for (int j = 0; j < 2; ++j)
                acc[i][j] = mfma_fp8_32x32_k64(a[i].v8, b[j].v8, acc[i][j]);
    };

    // ---- counted-vmcnt 2-buffer ring (depth-1 prefetch, 4 blocks/CU) ----
    stage(0, 0);                       // 4 outstanding
    stage(1, 1);                       // 8 outstanding

    VMWAIT(4);                         // own c0 loads done (c1 in flight)
    __builtin_amdgcn_s_barrier();      // everyone's c0 done
    body(As[0], Bs[0]);

    __builtin_amdgcn_s_barrier();      // all waves done READING buf0
    stage(0, 2);                       // c2 -> buf0; <=8 outstanding
    VMWAIT(4);                         // own c1 done (c2 in flight)
    __builtin_amdgcn_s_barrier();      // everyone's c1 done
    body(As[1], Bs[1]);

    __builtin_amdgcn_s_barrier();      // all waves done reading buf1
    stage(1, 3);                       // c3 -> buf1; <=8 outstanding
    VMWAIT(4);                         // own c2 done (c3 in flight)
    __builtin_amdgcn_s_barrier();      // everyone's c2 done
    body(As[0], Bs[0]);

    VMWAIT(0);                         // own c3 done (buf0 not rewritten)
    __builtin_amdgcn_s_barrier();      // everyone's c3 done
    body(As[1], Bs[1]);

    // Epilogue: z2 = s2*acc + b2 (log2 domain); log2 of products of 8.
    const float s2 = __expf(t_prime[0]) * LOG2E;
    const float b2 = bias[0] * LOG2E;
    float local = 0.0f;
#pragma unroll
    for (int i = 0; i < 2; ++i)
#pragma unroll
        for (int j = 0; j < 2; ++j)
#pragma unroll
            for (int g2 = 0; g2 < 2; ++g2) {
                float x[8];
#pragma unroll
                for (int e = 0; e < 8; ++e)
                    x[e] = exp2_fast(fmaf(s2, acc[i][j][g2 * 8 + e], b2));
                float p = 1.0f + x[0];
#pragma unroll
                for (int e = 1; e < 8; ++e)
                    p = fmaf(p, x[e], p);      // p *= (1 + x[e])
                local += log2_fast(p);
            }

    // Diagonal blocks: softplus(-z) = softplus(z) - z -> subtract z2.
    if (rowBase == colBase) {
#pragma unroll
        for (int i = 0; i < 2; ++i)
#pragma unroll
            for (int j = 0; j < 2; ++j)
#pragma unroll
                for (int r = 0; r < 16; ++r) {
                    // 32x32 C/D layout (m74/m101): col = lane&31,
                    // row = (r&3) + 8*(r>>2) + 4*(lane>>5)
                    int rowf = (r & 3) + 8 * (r >> 2) + 4 * g;
                    int grow = wv * 64 + i * 32 + rowf;
                    int gcol = wu * 64 + j * 32 + r31;
                    if (grow == gcol) local -= fmaf(s2, acc[i][j][r], b2);
                }
    }

#pragma unroll
    for (int off = 32; off > 0; off >>= 1)
        local += __shfl_xor(local, off, 64);
    if (lane == 0) red[wave] = local;
    __syncthreads();
    if (tid == 0)
        partials[bid] = (red[0] + red[1]) + (red[2] + red[3]);   // plain store
}

// Kernel 3: reduce 16384 per-block partials -> out[0]. One block, ~3 us.
__global__ __launch_bounds__(1024) void reduce_kernel(
    const float* __restrict__ partials, float* __restrict__ out, int N)
{
    __shared__ float red[16];
    const int tid  = threadIdx.x;
    const int wave = tid >> 6;
    const int lane = tid & 63;
    float s = 0.0f;
#pragma unroll 4
    for (int i = tid; i < NBLK; i += 1024)
        s += partials[i];
#pragma unroll
    for (int off = 32; off > 0; off >>= 1)
        s += __shfl_xor(s, off, 64);
    if (lane == 0) red[wave] = s;
    __syncthreads();
    if (tid == 0) {
        float t = 0.0f;
#pragma unroll
        for (int w = 0; w < 16; ++w) t += red[w];
        out[0] = t * (LN2 / (float)N);
    }
}

extern "C" void kernel_launch(void* const* d_in, const int* in_sizes, int n_in,
                              void* d_out, int out_size, void* d_ws, size_t ws_size,
                              hipStream_t stream) {
    const float* img = (const float*)d_in[0];
    const float* txt = (const float*)d_in[1];
    const float* tp  = (const float*)d_in[2];
    const float* bs  = (const float*)d_in[3];
    float* out = (float*)d_out;
    int N = in_sizes[0] / D_DIM;    // 16384

    unsigned char* Ab = (unsigned char*)d_ws;       // 4 MB (k-major strips)
    unsigned char* Bb = Ab + (size_t)N * D_DIM;     // +4 MB
    float* partials   = (float*)(Bb + (size_t)N * D_DIM);   // 64 KB

    norm_cast_kernel<<<(2 * N) / 16, 256, 0, stream>>>(img, txt, Ab, Bb, N);
    siglip_loss_kernel<<<NBLK, 256, 0, stream>>>(Ab, Bb, tp, bs, partials, N);
    reduce_kernel<<<1, 1024, 0, stream>>>(partials, out, N);
}